// Round 8
// baseline (359.876 us; speedup 1.0000x reference)
//
#include <hip/hip_runtime.h>
#include <math.h>

#define B_N 16384
#define C_N 250
#define D_N 2048
#define CP  256

// ---- workspace layout (float offsets) ----
// zeroed by front kernel (first dispatch): [0, 62564) = pp + scal
#define OFF_PP     0          // 62500
#define OFF_SCAL   62500      // 64
#define ZERO_F4    15641      // 62564 floats / 4
// non-zeroed (fully written before read):
#define OFF_CEPART 62564      // 1024 (per-block CE partials, plain stores)
#define OFF_BH     63588      // 16384 ints (per-chunk histograms)
#define OFF_OFFG   79972      // 260 ints (class offsets[257])
#define OFF_COUNTS 80232      // 256
#define OFF_SORT   80488      // 16384 ints (rows sorted by class)
#define OFF_CENT   96872      // 524288
#define OFF_GRAMP  621160     // 1048576 = 16 slices x 256x256
#define OFF_C2RAW  1669736    // 256
#define OFF_C2N    1669992    // 256
#define OFF_INVEN  1670248    // 16384
#define OFF_PSN    1686632    // 65536 = 4 quarters x 16384
#define OFF_CENTNB 1752168    // 262144 floats = 256x2048 bf16
#define T1_END     2014312
#define OFF_EBF    2014312    // 16777216 floats = 16384x2048 bf16 (UNnormalized)
#define T2_END     18791528   // ~75 MB (ws is ~512 MB per fill size)

// scal slots: float: 1=A1(sum pd^2) 2=A2(sum pd*Mn) 9=A3(sum Mn^2) 5=n_upper
//             10=margin_sum 6=n_pairs
// uint: 3=maxM bits, 4=pmax bits, 7=npresent, 8=ticket

typedef __bf16 bf16x8 __attribute__((ext_vector_type(8)));
typedef float  f32x4  __attribute__((ext_vector_type(4)));

__device__ __forceinline__ unsigned short bfbits(float x){
  unsigned u = __float_as_uint(x);
  return (unsigned short)((u + 0x7FFFu + ((u>>16)&1u)) >> 16);  // RNE
}

__device__ __forceinline__ void gload_lds16(const void* g, void* l){
  __builtin_amdgcn_global_load_lds(
      (const __attribute__((address_space(1))) unsigned*)g,
      (__attribute__((address_space(3))) unsigned*)l, 16, 0, 0);
}

__device__ __forceinline__ float warpSum(float v){
#pragma unroll
  for(int o=32;o;o>>=1) v += __shfl_xor(v,o,64);
  return v;
}
__device__ __forceinline__ float warpMax(float v){
#pragma unroll
  for(int o=32;o;o>>=1) v = fmaxf(v, __shfl_xor(v,o,64));
  return v;
}
__device__ __forceinline__ float blockSum256(float v){
  __shared__ float s[4];
  int lane = threadIdx.x & 63, w = threadIdx.x >> 6;
  v = warpSum(v);
  __syncthreads();
  if(lane==0) s[w]=v;
  __syncthreads();
  return s[0]+s[1]+s[2]+s[3];
}
__device__ __forceinline__ float blockMax256(float v){
  __shared__ float s[4];
  int lane = threadIdx.x & 63, w = threadIdx.x >> 6;
  v = warpMax(v);
  __syncthreads();
  if(lane==0) s[w]=v;
  __syncthreads();
  return fmaxf(fmaxf(s[0],s[1]), fmaxf(s[2],s[3]));
}

// ================= K1: CE (partials) + label hist + ws zero =================
// grid 1152: [0,1024) ce, [1024,1088) hist, [1088,1152) zero pp+scal.
// CE writes per-block partials (no atomic — avoids race with the zero blocks).
__global__ __launch_bounds__(256) void tgl_front(const float* __restrict__ logits,
                                                 const int* __restrict__ labels,
                                                 float* __restrict__ ce_part,
                                                 int* __restrict__ bh,
                                                 float* __restrict__ zbase){
  __shared__ int h[256];
  int b = blockIdx.x, t = threadIdx.x;
  if(b < 1024){
    int lane = t & 63, w = t >> 6;
    float lsum = 0.f;
#pragma unroll
    for(int u=0; u<4; ++u){
      int r = b*16 + w*4 + u;
      const float* row = logits + (size_t)r*C_N;
      float x0 = (lane     < C_N) ? row[lane]     : -1e30f;
      float x1 = (lane+64  < C_N) ? row[lane+64]  : -1e30f;
      float x2 = (lane+128 < C_N) ? row[lane+128] : -1e30f;
      float x3 = (lane+192 < C_N) ? row[lane+192] : -1e30f;
      float mx = warpMax(fmaxf(fmaxf(x0,x1), fmaxf(x2,x3)));
      float e = 0.f;
      if(lane     < C_N) e += expf(x0-mx);
      if(lane+64  < C_N) e += expf(x1-mx);
      if(lane+128 < C_N) e += expf(x2-mx);
      if(lane+192 < C_N) e += expf(x3-mx);
      e = warpSum(e);
      if(lane==0){
        int l = labels[r];
        lsum += -(row[l] - mx - logf(e));
      }
    }
    float tot = blockSum256(lsum);
    if(t==0) ce_part[b] = tot;
  } else if(b < 1088){
    h[t] = 0;
    __syncthreads();
    int hb = b - 1024;
    atomicAdd(&h[labels[hb*256 + t]], 1);
    __syncthreads();
    bh[hb*256 + t] = h[t];
  } else {
    int i4 = (b-1088)*256 + t;
    if(i4 < ZERO_F4) ((float4*)zbase)[i4] = make_float4(0,0,0,0);
  }
}

// ============ K2: redundant scan per block + scatter + max(M) ============
// grid 64. Each block recomputes the full class scan from bh (cheap, removes
// the serial single-block scan dispatch), scatters its 256 labels.
__global__ __launch_bounds__(256) void tgl_scansc(const int* __restrict__ bh,
                                                  const int* __restrict__ labels,
                                                  const float* __restrict__ M,
                                                  int* __restrict__ sorted,
                                                  int* __restrict__ offg,
                                                  float* __restrict__ counts,
                                                  unsigned* __restrict__ mxbits){
  __shared__ int ps[256];
  __shared__ int lofs[256];
  int t = threadIdx.x, b = blockIdx.x;
  float m = 0.f;
  for(int i = b*256 + t; i < C_N*C_N; i += 64*256) m = fmaxf(m, M[i]);
  m = blockMax256(m);
  if(t==0) atomicMax(mxbits, __float_as_uint(m));
  int mypart = 0, tot = 0;
#pragma unroll 8
  for(int bb=0; bb<64; bb++){
    int hh = bh[bb*256 + t];
    if(bb < b) mypart += hh;
    tot += hh;
  }
  ps[t] = tot;
  __syncthreads();
  for(int o=1;o<256;o<<=1){
    int v = (t>=o) ? ps[t-o] : 0;
    __syncthreads();
    ps[t] += v;
    __syncthreads();
  }
  int excl = ps[t] - tot;
  if(b==0){
    offg[t] = excl;
    if(t==255) offg[256] = ps[255];
    counts[t] = (float)tot;
  }
  lofs[t] = excl + mypart;
  __syncthreads();
  int r = b*256 + t;
  int pos = atomicAdd(&lofs[labels[r]], 1);
  sorted[pos] = r;
}

// ================= K3: class-gather segment sum =================
// grid (250, 4 D-quarters). 4 rows / wave-iter = 8x1KB loads in flight.
__device__ __forceinline__ void gproc(int row, int hq, float4 v0, float4 v1,
                                      f32x4& acc0, f32x4& acc1,
                                      float* __restrict__ psn,
                                      unsigned short* __restrict__ ebf,
                                      int l, int d0, bool do_ebf){
  float sq = v0.x*v0.x+v0.y*v0.y+v0.z*v0.z+v0.w*v0.w
           + v1.x*v1.x+v1.y*v1.y+v1.z*v1.z+v1.w*v1.w;
  sq = warpSum(sq);
  if(l==0) psn[(size_t)hq*B_N + row] = sq;
  if(do_ebf){
    unsigned short* o = ebf + (size_t)row*D_N + d0;
    ushort4 hb;
    hb.x=bfbits(v0.x); hb.y=bfbits(v0.y); hb.z=bfbits(v0.z); hb.w=bfbits(v0.w);
    *(ushort4*)&o[l*4] = hb;
    hb.x=bfbits(v1.x); hb.y=bfbits(v1.y); hb.z=bfbits(v1.z); hb.w=bfbits(v1.w);
    *(ushort4*)&o[256 + l*4] = hb;
  }
  acc0[0]+=v0.x; acc0[1]+=v0.y; acc0[2]+=v0.z; acc0[3]+=v0.w;
  acc1[0]+=v1.x; acc1[1]+=v1.y; acc1[2]+=v1.z; acc1[3]+=v1.w;
}

template<bool EBF>
__global__ __launch_bounds__(256) void tgl_gather(const float* __restrict__ emb,
                                                  const int* __restrict__ sorted,
                                                  const int* __restrict__ offg,
                                                  float* __restrict__ cent,
                                                  float* __restrict__ psn,
                                                  unsigned short* __restrict__ ebf){
  __shared__ float red[2048];
  int t = threadIdx.x, l = t & 63, w = t >> 6;
  int c = blockIdx.x, h = blockIdx.y;
  int d0 = h*512;
  int off = offg[c];
  int cnt = offg[c+1] - off;
  const int* rows = sorted + off;
  f32x4 acc0 = {}, acc1 = {};
  int k = w;
  for(; k+12 < cnt; k += 16){
    int r0 = rows[k], r1 = rows[k+4], r2 = rows[k+8], r3 = rows[k+12];
    const float* p0 = emb + (size_t)r0*D_N + d0;
    const float* p1 = emb + (size_t)r1*D_N + d0;
    const float* p2 = emb + (size_t)r2*D_N + d0;
    const float* p3 = emb + (size_t)r3*D_N + d0;
    float4 a0 = *(const float4*)&p0[l*4], a1 = *(const float4*)&p0[256+l*4];
    float4 b0 = *(const float4*)&p1[l*4], b1 = *(const float4*)&p1[256+l*4];
    float4 e0 = *(const float4*)&p2[l*4], e1 = *(const float4*)&p2[256+l*4];
    float4 f0 = *(const float4*)&p3[l*4], f1 = *(const float4*)&p3[256+l*4];
    gproc(r0, h, a0, a1, acc0, acc1, psn, ebf, l, d0, EBF);
    gproc(r1, h, b0, b1, acc0, acc1, psn, ebf, l, d0, EBF);
    gproc(r2, h, e0, e1, acc0, acc1, psn, ebf, l, d0, EBF);
    gproc(r3, h, f0, f1, acc0, acc1, psn, ebf, l, d0, EBF);
  }
  for(; k < cnt; k += 4){
    int r0 = rows[k];
    const float* p0 = emb + (size_t)r0*D_N + d0;
    float4 a0 = *(const float4*)&p0[l*4], a1 = *(const float4*)&p0[256+l*4];
    gproc(r0, h, a0, a1, acc0, acc1, psn, ebf, l, d0, EBF);
  }
  __syncthreads();
  *(f32x4*)&red[w*512 + l*4]       = acc0;
  *(f32x4*)&red[w*512 + 256 + l*4] = acc1;
  __syncthreads();
  if(t < 128){
    f32x4 s = *(f32x4*)&red[t*4];
#pragma unroll
    for(int ww=1; ww<4; ww++){
      f32x4 r2 = *(f32x4*)&red[ww*512 + t*4];
      s[0]+=r2[0]; s[1]+=r2[1]; s[2]+=r2[2]; s[3]+=r2[3];
    }
    *(f32x4*)&cent[(size_t)c*D_N + d0 + t*4] = s;
  }
}

// ================= K4: centroid finalize (+fused inv_en) =================
__global__ __launch_bounds__(256) void tgl_cfin(float* __restrict__ cent,
                                                const float* __restrict__ counts,
                                                const float* __restrict__ psn,
                                                float* __restrict__ inv_en,
                                                unsigned short* __restrict__ centnb,
                                                float* __restrict__ c2raw,
                                                float* __restrict__ c2n,
                                                unsigned* __restrict__ npresent){
  __shared__ float sval[D_N];
  __shared__ float s_inv;
  int c = blockIdx.x, t = threadIdx.x, l = t & 63, w = t >> 6;
  if(w==0){
    int r = c*64 + l;
    float sn = psn[r] + psn[B_N + r] + psn[2*B_N + r] + psn[3*B_N + r];
    inv_en[r] = 1.f / fmaxf(sqrtf(sn), 1e-12f);
  }
  if(c >= C_N){
    for(int d=t; d<D_N; d+=256) centnb[(size_t)c*D_N + d] = 0;
    return;
  }
  float cnt = counts[c];
  float ic = 1.f / fmaxf(cnt, 1.f);
  float ss = 0.f;
  for(int d=t; d<D_N; d+=256){
    float v = cent[(size_t)c*D_N + d]*ic;
    sval[d] = v;
    ss += v*v;
  }
  ss = blockSum256(ss);
  if(t==0){
    c2raw[c] = ss;
    float inv = 1.f / fmaxf(sqrtf(ss), 1e-12f);
    c2n[c] = ss*inv*inv;
    s_inv = inv;
    if(cnt > 0.f) atomicAdd(npresent, 1u);
  }
  __syncthreads();
  float inv = s_inv;
  for(int d=t; d<D_N; d+=256){
    float v = sval[d];
    cent[(size_t)c*D_N + d] = v;
    centnb[(size_t)c*D_N + d] = bfbits(v*inv);
  }
}

// ========== K5: margin GEMM (blocks 0-511) | gram k-split (512-767) ==========
template<bool EBF>
__global__ __launch_bounds__(256) void tgl_gm(const unsigned short* __restrict__ ebf,
                                              const float* __restrict__ emb,
                                              const float* __restrict__ inv_en,
                                              const unsigned short* __restrict__ centnb,
                                              const int* __restrict__ labels,
                                              const float* __restrict__ c2n,
                                              float* __restrict__ pp,
                                              const float* __restrict__ cent,
                                              float* __restrict__ gramp){
  __shared__ __align__(16) unsigned char smem[24576];
  int t = threadIdx.x, b = blockIdx.x;
  if(b < 512){
    // ---- margin: 64x128 tile, BK=64, XOR-swizzled LDS (R7-proven) ----
    unsigned short* at = (unsigned short*)smem;          // 64x64 bf16 = 8KB
    unsigned short* bt = (unsigned short*)(smem + 8192); // 128x64 bf16 = 16KB
    int w = t>>6, l = t&63;
    int s0 = (b>>1)*64, c0 = (b&1)*128;
    int wm = w>>1, wn = w&1;
    f32x4 acc[2][4] = {};
    for(int kk=0; kk<D_N; kk+=64){
      __syncthreads();
#pragma unroll
      for(int q=0;q<4;q++){
        int row = q*32 + w*8 + (l>>3);
        int kslot = l&7;
        int gk = kk + ((kslot ^ (row&7))<<3);
        gload_lds16(centnb + (size_t)(c0+row)*D_N + gk, &bt[row*64 + kslot*8]);
      }
#pragma unroll
      for(int q=0;q<2;q++){
        int row = q*32 + w*8 + (l>>3);
        int kslot = l&7;
        int gk = kk + ((kslot ^ (row&7))<<3);
        if constexpr(EBF)
          gload_lds16(ebf + (size_t)(s0+row)*D_N + gk, &at[row*64 + kslot*8]);
      }
      if constexpr(!EBF){
#pragma unroll
        for(int q=0;q<4;q++){
          int v = t + q*256;
          int row = v>>4, kq = v&15;
          float4 f = *(const float4*)&emb[(size_t)(s0+row)*D_N + kk + kq*4];
          ushort4 hb;
          hb.x = bfbits(f.x); hb.y = bfbits(f.y); hb.z = bfbits(f.z); hb.w = bfbits(f.w);
          int j = (kq>>1) ^ (row&7);
          *(ushort4*)&at[row*64 + j*8 + (kq&1)*4] = hb;
        }
      }
      __syncthreads();
#pragma unroll
      for(int s=0;s<2;s++){
        bf16x8 af[2], bf[4];
#pragma unroll
        for(int i=0;i<2;i++){
          int m = wm*32 + i*16 + (l&15);
          int j = s*4 + (l>>4);
          af[i] = *(const bf16x8*)&at[m*64 + ((j ^ (m&7))<<3)];
        }
#pragma unroll
        for(int jj=0;jj<4;jj++){
          int n = wn*64 + jj*16 + (l&15);
          int j = s*4 + (l>>4);
          bf[jj] = *(const bf16x8*)&bt[n*64 + ((j ^ (n&7))<<3)];
        }
#pragma unroll
        for(int i=0;i<2;i++)
#pragma unroll
          for(int jj=0;jj<4;jj++)
            acc[i][jj] = __builtin_amdgcn_mfma_f32_16x16x32_bf16(af[i], bf[jj], acc[i][jj], 0,0,0);
      }
    }
#pragma unroll
    for(int i=0;i<2;i++){
#pragma unroll
      for(int r=0;r<4;r++){
        int s = s0 + wm*32 + i*16 + (l>>4)*4 + r;
        int lab = labels[s];
        float inv = inv_en[s];
#pragma unroll
        for(int jj=0;jj<4;jj++){
          int c = c0 + wn*64 + jj*16 + (l&15);
          if(c < C_N){
            float dot = acc[i][jj][r]*inv;
            float d2 = 1.f + c2n[c] - 2.f*dot;
            float hh = 1.2f - sqrtf(fmaxf(d2, 0.f));
            if(hh > 0.f) atomicAdd(&pp[(size_t)lab*C_N + c], hh);
          }
        }
      }
    }
  } else {
    // ---- gram: 64x64 tile, k-split 16, non-atomic slabs ----
    float (*atf)[36] = (float(*)[36])smem;
    float (*btf)[36] = (float(*)[36])(smem + 9216);
    int gb = b - 512;
    int tx = t & 15, ty = t >> 4;
    int i0 = (gb&3)*64, j0 = ((gb>>2)&3)*64, k0 = (gb>>4)*128;
    float acc[4][4] = {};
    for(int kk=k0; kk<k0+128; kk+=32){
      __syncthreads();
#pragma unroll
      for(int u=0;u<2;u++){
        int v = t + u*256; int r = v>>3, q = (v&7)*4;
        float4 a = (i0+r < C_N) ? *(const float4*)&cent[(size_t)(i0+r)*D_N + kk + q] : make_float4(0,0,0,0);
        *(float4*)&atf[r][q] = a;
        float4 bb = (j0+r < C_N) ? *(const float4*)&cent[(size_t)(j0+r)*D_N + kk + q] : make_float4(0,0,0,0);
        *(float4*)&btf[r][q] = bb;
      }
      __syncthreads();
#pragma unroll
      for(int kq=0;kq<8;kq++){
        float4 a[4], bb[4];
#pragma unroll
        for(int i=0;i<4;i++) a[i] = *(float4*)&atf[ty*4+i][kq*4];
#pragma unroll
        for(int j=0;j<4;j++) bb[j] = *(float4*)&btf[tx+16*j][kq*4];
#pragma unroll
        for(int i=0;i<4;i++)
#pragma unroll
          for(int j=0;j<4;j++)
            acc[i][j] += a[i].x*bb[j].x + a[i].y*bb[j].y + a[i].z*bb[j].z + a[i].w*bb[j].w;
      }
    }
    float* slab = gramp + (size_t)(gb>>4)*65536;
#pragma unroll
    for(int i=0;i<4;i++)
#pragma unroll
      for(int j=0;j<4;j++)
        slab[(size_t)(i0+ty*4+i)*CP + (j0+tx+16*j)] = acc[i][j];
  }
}

// ====== K6: pdist + pmax + topo/margin partials + final (ticket counter) =====
// topo decomposed pmax-free: sum(pd*ip - Mn)^2 = ip^2*A1 - 2*ip*A2 + A3.
// All cross-block comms via device-scope atomics (G16-safe); last ticket
// block combines and writes out[].
__global__ __launch_bounds__(256) void tgl_pt(const float* __restrict__ gramp,
                                              const float* __restrict__ c2raw,
                                              const float* __restrict__ counts,
                                              const float* __restrict__ M,
                                              const float* __restrict__ pp,
                                              const float* __restrict__ ce_part,
                                              float* __restrict__ scal,
                                              float* __restrict__ out){
  __shared__ int sflag;
  int t = threadIdx.x;
  int idx = blockIdx.x*256 + t;
  unsigned* su = (unsigned*)scal;
  float inv_maxM = 1.f / scal[3];   // bits stored by K2 atomicMax, valid float
  float lpm = 0.f;
  float a1=0.f, a2=0.f, a3=0.f, c1=0.f, s2=0.f, c2=0.f;
  if(idx < C_N*C_N){
    int i = idx / C_N, j = idx % C_N;
    float g = 0.f;
#pragma unroll
    for(int s=0; s<16; s++) g += gramp[(size_t)s*65536 + (size_t)i*CP + j];
    float ps = c2raw[i] + c2raw[j] - 2.f*g;
    float pd = sqrtf(fmaxf(ps, 0.f) + 1e-12f);
    bool both = counts[i] > 0.f && counts[j] > 0.f;
    if(both) lpm = pd;
    float Mn = M[idx]*inv_maxM;
    if(j > i && both){ a1 += pd*pd; a2 += pd*Mn; a3 += Mn*Mn; c1 += 1.f; }
    if(i != j && both && Mn < 0.3f){ s2 += pp[idx]/fmaxf(counts[i],1.f); c2 += 1.f; }
  }
  lpm = blockMax256(lpm);
  a1 = blockSum256(a1); a2 = blockSum256(a2); a3 = blockSum256(a3);
  c1 = blockSum256(c1); s2 = blockSum256(s2); c2 = blockSum256(c2);
  if(t==0){
    atomicMax(&su[4], __float_as_uint(lpm));
    atomicAdd(&scal[1], a1); atomicAdd(&scal[2], a2); atomicAdd(&scal[9], a3);
    atomicAdd(&scal[5], c1); atomicAdd(&scal[10], s2); atomicAdd(&scal[6], c2);
    __threadfence();
    unsigned tick = atomicAdd(&su[8], 1u);
    sflag = (tick == gridDim.x - 1) ? 1 : 0;
  }
  __syncthreads();
  if(sflag){
    float cs = 0.f;
    for(int i=t; i<1024; i+=256) cs += ce_part[i];   // plain: written prev dispatch
    cs = blockSum256(cs);
    if(t==0){
      float pmax = __uint_as_float(atomicMax(&su[4], 0u));
      float A1 = atomicAdd(&scal[1], 0.f);
      float A2 = atomicAdd(&scal[2], 0.f);
      float A3 = atomicAdd(&scal[9], 0.f);
      float nu = atomicAdd(&scal[5], 0.f);
      float S2 = atomicAdd(&scal[10], 0.f);
      float np = atomicAdd(&scal[6], 0.f);
      unsigned npr = atomicAdd(&su[7], 0u);
      float ip = 1.f / pmax;
      float tsum = ip*ip*A1 - 2.f*ip*A2 + A3;
      int gate = npr >= 2u;
      float topo   = gate ? tsum / fmaxf(nu, 1.f) : 0.f;
      float margin = (gate && np > 0.f) ? S2 / fmaxf(np, 1.f) : 0.f;
      float ce = cs / (float)B_N;
      out[0] = ce + 0.1f*topo + 0.05f*margin;
      out[1] = ce;
      out[2] = topo;
      out[3] = margin;
    }
  }
}

extern "C" void kernel_launch(void* const* d_in, const int* in_sizes, int n_in,
                              void* d_out, int out_size, void* d_ws, size_t ws_size,
                              hipStream_t stream){
  const float* logits = (const float*)d_in[0];
  const int*   labels = (const int*)d_in[1];
  const float* emb    = (const float*)d_in[2];
  const float* M      = (const float*)d_in[3];
  float* out = (float*)d_out;
  float* ws  = (float*)d_ws;

  float* pp      = ws + OFF_PP;
  float* scal    = ws + OFF_SCAL;
  float* ce_part = ws + OFF_CEPART;
  int*   bh      = (int*)(ws + OFF_BH);
  int*   offg    = (int*)(ws + OFF_OFFG);
  float* counts  = ws + OFF_COUNTS;
  int*   sorted  = (int*)(ws + OFF_SORT);
  float* cent    = ws + OFF_CENT;
  float* gramp   = ws + OFF_GRAMP;
  float* c2raw   = ws + OFF_C2RAW;
  float* c2n     = ws + OFF_C2N;
  float* inv_en  = ws + OFF_INVEN;
  float* psn     = ws + OFF_PSN;
  unsigned short* centnb = (unsigned short*)(ws + OFF_CENTNB);
  unsigned short* ebf    = (unsigned short*)(ws + OFF_EBF);
  unsigned* scal_u = (unsigned*)scal;

  bool use_ebf = (ws_size / sizeof(float)) >= (size_t)T2_END;

  tgl_front<<<1152, 256, 0, stream>>>(logits, labels, ce_part, bh, ws);
  tgl_scansc<<<64, 256, 0, stream>>>(bh, labels, M, sorted, offg, counts, &scal_u[3]);
  {
    dim3 g(C_N, 4);
    if(use_ebf) tgl_gather<true ><<<g, 256, 0, stream>>>(emb, sorted, offg, cent, psn, ebf);
    else        tgl_gather<false><<<g, 256, 0, stream>>>(emb, sorted, offg, cent, psn, ebf);
  }
  tgl_cfin<<<CP, 256, 0, stream>>>(cent, counts, psn, inv_en, centnb, c2raw, c2n, &scal_u[7]);
  if(use_ebf) tgl_gm<true ><<<768, 256, 0, stream>>>(ebf, emb, inv_en, centnb, labels, c2n, pp, cent, gramp);
  else        tgl_gm<false><<<768, 256, 0, stream>>>(ebf, emb, inv_en, centnb, labels, c2n, pp, cent, gramp);
  tgl_pt<<<(C_N*C_N + 255)/256, 256, 0, stream>>>(gramp, c2raw, counts, M, pp, ce_part, scal, out);
}